// Round 16
// baseline (513.059 us; speedup 1.0000x reference)
//
#include <hip/hip_runtime.h>
#include <math.h>

// QLinear via int8, chunk-major operands:
//   y = (sum_k xq[r][k]*Wq[c][k]) * sx[r] * scale[c]
// xqt/wqt layout: [k_chunk][row] of 16-byte chunks (chunk = k/16).
// A fragments load DIRECTLY global->VGPR (coalesced); only B goes through LDS.
#define M_DIM 8192
#define N_DIM 11008
#define K_DIM 4096

#define BM 256
#define BN 128
#define BKB 64                     // K-bytes per tile -> 4 chunks
#define NT (K_DIM / BKB)           // 64
#define NBN (N_DIM / BN)           // 86
#define NWG ((M_DIM / BM) * NBN)   // 2752 (divisible by 8)

#define CHUNK_A_STRIDE (M_DIM * 16)   // bytes between A chunks
#define CHUNK_B_STRIDE (N_DIM * 16)   // bytes between B chunks

typedef int int4v __attribute__((ext_vector_type(4)));
typedef int int16v __attribute__((ext_vector_type(16)));

__device__ __forceinline__ void async_copy16(const void* g, void* l) {
  __builtin_amdgcn_global_load_lds(
      (const __attribute__((address_space(1))) void*)g,
      (__attribute__((address_space(3))) void*)l, 16, 0, 0);
}

// ---- x quantization -> chunk-major xqt[c][row] (scattered 16B writes) ----
__global__ __launch_bounds__(256) void quant_x(const float* __restrict__ x,
                                               signed char* __restrict__ xqt,
                                               float* __restrict__ sx) {
  __shared__ float wred[4];
  const int row = blockIdx.x;
  const int tid = threadIdx.x;   // tid == chunk index within row
  const float4* src = (const float4*)(x + (size_t)row * K_DIM) + tid * 4;
  float4 v0 = src[0], v1 = src[1], v2 = src[2], v3 = src[3];

  float m = 0.f;
#define MX4(V) m = fmaxf(m, fmaxf(fmaxf(fabsf(V.x), fabsf(V.y)), fmaxf(fabsf(V.z), fabsf(V.w))))
  MX4(v0); MX4(v1); MX4(v2); MX4(v3);
#undef MX4
#pragma unroll
  for (int off = 32; off >= 1; off >>= 1)
    m = fmaxf(m, __shfl_xor(m, off, 64));
  if ((tid & 63) == 0) wred[tid >> 6] = m;
  __syncthreads();
  float smax = fmaxf(fmaxf(wred[0], wred[1]), fmaxf(wred[2], wred[3]));
  smax = fmaxf(smax, 1e-20f);
  const float inv = 127.f / smax;

  int4v o;
#define Q4(V, G) o[G] = ((int)rintf(V.x * inv) & 255) | (((int)rintf(V.y * inv) & 255) << 8) | \
                        (((int)rintf(V.z * inv) & 255) << 16) | (((int)rintf(V.w * inv) & 255) << 24)
  Q4(v0, 0); Q4(v1, 1); Q4(v2, 2); Q4(v3, 3);
#undef Q4
  ((int4v*)xqt)[(size_t)tid * M_DIM + row] = o;   // [chunk][row]
  if (tid == 0) sx[row] = smax / 127.f;
}

// ---- W pack -> chunk-major wqt[c][col]; one (col-group, chunk) per block ----
__global__ __launch_bounds__(256) void pack_w(const int* __restrict__ in,
                                              signed char* __restrict__ wqt) {
  const int cg = blockIdx.x % (N_DIM / 256);   // col group (43)
  const int c = blockIdx.x / (N_DIM / 256);    // chunk (256)
  const int col = cg * 256 + threadIdx.x;
  const int4* src = (const int4*)(in + (size_t)col * K_DIM + c * 16);
  int4 a = src[0], b = src[1], d = src[2], e = src[3];
  int4v o;
  o[0] = a.x | (a.y << 8) | (a.z << 16) | (a.w << 24);
  o[1] = b.x | (b.y << 8) | (b.z << 16) | (b.w << 24);
  o[2] = d.x | (d.y << 8) | (d.z << 16) | (d.w << 24);
  o[3] = e.x | (e.y << 8) | (e.z << 16) | (e.w << 24);
  ((int4v*)wqt)[(size_t)c * N_DIM + col] = o;   // [chunk][col] — coalesced
}

// ---- main GEMM: 256x128 tile, 8 waves 4x2 (64x64/wave), BKB=64.
// A: direct global->reg, chunk-major (coalesced), X/Y double-buffered regs.
// B: LDS [chunk][col] (4 x 2 KiB = 8 KiB/tile), double-buffered, staged by
// ONE global_load_lds per thread; reads are 512B-contiguous => 0 conflicts.
// R12 sync skeleton: prefetch at top, vmcnt(0)+barrier at bottom; 16 KiB LDS
// + <=128 regs => 2 blocks/CU cover the drain stall.
// C/D: col=lane&31, row=(reg&3)+8*(reg>>2)+4*(lane>>5) [R9-R15 HW-ok]. ----
__global__ __launch_bounds__(512, 4) void gemm_i8(
    const signed char* __restrict__ A, const signed char* __restrict__ B,
    const float* __restrict__ scale, const float* __restrict__ sx,
    float* __restrict__ out) {
  __shared__ __align__(16) char smw[16384];  // 2 x 8 KiB B buffers
  const int tid = threadIdx.x;
  const int lane = tid & 63;
  const int wv = tid >> 6;
  const int wr = wv >> 1, wc = wv & 1;   // 4x2 grid, 64x64 out/wave
  const int l31 = lane & 31;
  const int h = lane >> 5;

  int id = blockIdx.x;                   // T1: bijective XCD swizzle
  id = (id & 7) * (NWG / 8) + (id >> 3);
  const int bn = (id % NBN) * BN;
  const int bm = (id / NBN) * BM;

  int16v acc[2][2] = {};                 // 64 accum regs

  // per-wave A base: row (bm + wr*64 + l31), chunk-half h
  const signed char* Abase =
      A + (size_t)h * CHUNK_A_STRIDE + (size_t)(bm + wr * 64 + l31) * 16;
  // B stage source: thread covers (chunk tid>>7, col tid&127)
  const signed char* Bsrc0 =
      B + (size_t)(tid >> 7) * CHUNK_B_STRIDE + (size_t)(bn + (tid & 127)) * 16;

#define STAGE_B(T, OFF) \
  async_copy16(Bsrc0 + (size_t)(4 * (T)) * CHUNK_B_STRIDE, smw + (OFF) + tid * 16)

#define LOAD_A(T, SET)                                                        \
  _Pragma("unroll") for (int ks = 0; ks < 2; ++ks)                            \
  _Pragma("unroll") for (int mi = 0; mi < 2; ++mi)                            \
    SET[ks][mi] = *(const int4v*)(Abase +                                     \
        (size_t)(4 * (T) + 2 * ks) * CHUNK_A_STRIDE + mi * 32 * 16);

#define COMPUTE(SET, OFF)                                                     \
  _Pragma("unroll") for (int ks = 0; ks < 2; ++ks) {                          \
    int4v bfr[2];                                                             \
    _Pragma("unroll") for (int ni = 0; ni < 2; ++ni)                          \
      bfr[ni] = *(const int4v*)(smw + (OFF) + (2 * ks + h) * 2048 +           \
                                (wc * 64 + ni * 32 + l31) * 16);              \
    __builtin_amdgcn_s_setprio(1);                                            \
    _Pragma("unroll") for (int mi = 0; mi < 2; ++mi)                          \
    _Pragma("unroll") for (int ni = 0; ni < 2; ++ni)                          \
      acc[mi][ni] = __builtin_amdgcn_mfma_i32_32x32x32_i8(                    \
          SET[ks][mi], bfr[ni], acc[mi][ni], 0, 0, 0);                        \
    __builtin_amdgcn_s_setprio(0);                                            \
  }

  int4v AX[2][2], AY[2][2];

  // prologue: tile 0 -> buf0 + AX
  STAGE_B(0, 0);
  LOAD_A(0, AX);
  asm volatile("s_waitcnt vmcnt(0)" ::: "memory");
  __builtin_amdgcn_s_barrier();

#pragma unroll 1
  for (int t = 0; t < NT; t += 2) {
    // tile t (buf0, AX); prefetch t+1 -> buf1 + AY  (t+1 <= 63 always)
    STAGE_B(t + 1, 8192);
    LOAD_A(t + 1, AY);
    COMPUTE(AX, 0);
    asm volatile("s_waitcnt vmcnt(0)" ::: "memory");
    __builtin_amdgcn_s_barrier();

    // tile t+1 (buf1, AY); prefetch t+2 -> buf0 + AX
    if (t + 2 < NT) {
      STAGE_B(t + 2, 0);
      LOAD_A(t + 2, AX);
    }
    COMPUTE(AY, 8192);
    if (t + 2 < NT) {
      asm volatile("s_waitcnt vmcnt(0)" ::: "memory");
      __builtin_amdgcn_s_barrier();
    }
  }

  // epilogue: y = acc * sx[row] * scale[col]; 32x32 C/D layout
  const int ocol0 = bn + wc * 64 + l31;
  const int orow0 = bm + wr * 64 + 4 * h;
#pragma unroll
  for (int ni = 0; ni < 2; ++ni) {
    const float sc = scale[ocol0 + ni * 32];
#pragma unroll
    for (int mi = 0; mi < 2; ++mi) {
#pragma unroll
      for (int reg = 0; reg < 16; ++reg) {
        const int row = orow0 + mi * 32 + (reg & 3) + 8 * (reg >> 2);
        out[(size_t)row * N_DIM + ocol0 + ni * 32] =
            (float)acc[mi][ni][reg] * sx[row] * sc;
      }
    }
  }
#undef STAGE_B
#undef LOAD_A
#undef COMPUTE
}

// ---- fallback (only if ws too small): fp32 LDS-tiled, correct but slow ----
__global__ __launch_bounds__(256) void gemm_fallback(
    const float* __restrict__ X, const int* __restrict__ Wq,
    const float* __restrict__ scale, float* __restrict__ out) {
  __shared__ float Xs[64][17];
  __shared__ float Ws[64][17];
  const int tid = threadIdx.x;
  const int tn = blockIdx.x % (N_DIM / 64);
  const int tm = blockIdx.x / (N_DIM / 64);
  const int tr = tid >> 4, tc = tid & 15;
  float acc[4][4] = {};
  for (int k0 = 0; k0 < K_DIM; k0 += 16) {
#pragma unroll
    for (int i = 0; i < 4; ++i) {
      int idx = tid + i * 256;
      int r = idx >> 4, c = idx & 15;
      Xs[r][c] = X[(size_t)(tm * 64 + r) * K_DIM + k0 + c];
      Ws[r][c] = (float)Wq[(size_t)(tn * 64 + r) * K_DIM + k0 + c];
    }
    __syncthreads();
#pragma unroll
    for (int kk = 0; kk < 16; ++kk)
#pragma unroll
      for (int i = 0; i < 4; ++i) {
        float a = Xs[tr * 4 + i][kk];
#pragma unroll
        for (int j = 0; j < 4; ++j) acc[i][j] += a * Ws[tc * 4 + j][kk];
      }
    __syncthreads();
  }
#pragma unroll
  for (int i = 0; i < 4; ++i)
#pragma unroll
    for (int j = 0; j < 4; ++j) {
      int row = tm * 64 + tr * 4 + i, col = tn * 64 + tc * 4 + j;
      out[(size_t)row * N_DIM + col] = acc[i][j] * scale[col];
    }
}

extern "C" void kernel_launch(void* const* d_in, const int* in_sizes, int n_in,
                              void* d_out, int out_size, void* d_ws, size_t ws_size,
                              hipStream_t stream) {
  const float* x = (const float*)d_in[0];
  const int* Wq = (const int*)d_in[1];
  const float* scale = (const float*)d_in[2];
  float* out = (float*)d_out;

  const size_t XN = (size_t)M_DIM * K_DIM;   // 33,554,432
  const size_t WN = (size_t)N_DIM * K_DIM;   // 45,088,768
  const size_t need = XN + WN + M_DIM * sizeof(float);

  if (ws_size >= need) {
    signed char* xqt = (signed char*)d_ws;
    signed char* wqt = xqt + XN;
    float* sx = (float*)(wqt + WN);
    quant_x<<<M_DIM, 256, 0, stream>>>(x, xqt, sx);
    pack_w<<<(N_DIM / 256) * 256, 256, 0, stream>>>(Wq, wqt);
    gemm_i8<<<NWG, 512, 0, stream>>>(xqt, wqt, scale, sx, out);
  } else {
    gemm_fallback<<<(N_DIM / 64) * (M_DIM / 64), 256, 0, stream>>>(x, Wq, scale, out);
  }
}